// Round 2
// baseline (412.772 us; speedup 1.0000x reference)
//
#include <hip/hip_runtime.h>
#include <stdint.h>

#define NCELL (512 * 512)
#define DIN   136

// output layout (flat f32, concat in return order)
#define OUT_LAT 2097152ull                 // N*8
#define OUT_C   35651584ull                // OUT_LAT + N*128
#define OUT_H   52428800ull                // OUT_C + N*64

// packed-weight offsets in d_ws (bf16 elements)
#define WPRE_OFF  0        // [5][64][32]   = 10240
#define W2_OFF    10240    // [4][256][32]  = 32768
#define WPOST_OFF 43008    // [2][144][32]  = 9216
#define WTOTAL    52224

#define ROWB 336           // LDS bytes per cell-row (21*16; 5r mod 8 spreads bank slots)

typedef __bf16 bf16x8 __attribute__((ext_vector_type(8)));
typedef float  f32x4  __attribute__((ext_vector_type(4)));

__device__ __forceinline__ unsigned short f2bf(float f) {
    unsigned int u = __float_as_uint(f);
    u += 0x7FFF + ((u >> 16) & 1);          // round-to-nearest-even
    return (unsigned short)(u >> 16);
}
__device__ __forceinline__ int pack2(float a, float b) {
    return (int)f2bf(a) | ((int)f2bf(b) << 16);
}
__device__ __forceinline__ float fast_sigmoid(float x) {
    return __builtin_amdgcn_rcpf(1.f + __expf(-x));
}
__device__ __forceinline__ float fast_tanh(float x) {
    float e = __expf(2.f * x);              // inf-safe: rcp(inf)=0 -> 1; e->0 -> -1
    return 1.f - 2.f * __builtin_amdgcn_rcpf(e + 1.f);
}

// Repack weights to bf16, MFMA-B-fragment-friendly: [K/32][Ncol][32]
__global__ void prep_weights(const float* __restrict__ Wpre,
                             const float* __restrict__ Wih,
                             const float* __restrict__ Whh,
                             const float* __restrict__ Wpost,
                             unsigned short* __restrict__ ws) {
    int i = blockIdx.x * 256 + threadIdx.x;
    if (i < 10240) {                                   // Wpre' : K 136->160 pad, N=64
        int k = i & 31, n = (i >> 5) & 63, s = i >> 11;
        int K = s * 32 + k;
        ws[i] = (K < DIN) ? f2bf(Wpre[K * 64 + n]) : (unsigned short)0;
    } else if (i < 43008) {                            // W2'   : K=128 (ih||hh), N=256
        int j = i - 10240;
        int k = j & 31, n = (j >> 5) & 255, s = j >> 13;
        int K = s * 32 + k;
        float v = (K < 64) ? Wih[K * 256 + n] : Whh[(K - 64) * 256 + n];
        ws[i] = f2bf(v);
    } else if (i < WTOTAL) {                           // Wpost': K=64, N 136->144 pad
        int j = i - 43008;
        int k = j & 31;
        int t = j >> 5;
        int n = t % 144;
        int s = t / 144;
        int K = s * 32 + k;
        ws[i] = (n < DIN) ? f2bf(Wpost[K * DIN + n]) : (unsigned short)0;
    }
}

// Fused, barrier-free: each wave owns 16 cells end-to-end.
// LDS row r of wave w = Ls + (w*16+r)*ROWB:
//   phase0/GEMM1 : X bf16 cols 0..159 (bytes 0..319; 272..319 zero pad)
//   phase1.5     : pre -> bytes 0..127, h -> bytes 128..255 (overwrites X after fence)
//   phase2 LSTM  : hn -> bytes 0..127 (overwrites pre; pre cached in regs)
__global__ __launch_bounds__(256, 7) void knet_fused(
    const float* __restrict__ dyn_in,
    const float* __restrict__ lat_prev,
    const float* __restrict__ lstm_c,
    const float* __restrict__ lstm_h,
    const int*   __restrict__ coming_from,
    const unsigned short* __restrict__ wsp,
    const float* __restrict__ b_pre,
    const float* __restrict__ b_lstm,
    const float* __restrict__ b_post,
    float* __restrict__ out) {
    __shared__ __align__(16) char Ls[64 * ROWB];

    const int t    = threadIdx.x;
    const int lane = t & 63;
    const int w    = t >> 6;
    const int lr   = lane & 15;
    const int lg   = lane >> 4;
    const int cbase = blockIdx.x * 64 + w * 16;      // wave's first cell
    char* rowp = Ls + (size_t)(w * 16) * ROWB;       // wave-private 16 rows

    const unsigned short* wpre_p  = wsp + WPRE_OFF;
    const unsigned short* w2_p    = wsp + W2_OFF;
    const unsigned short* wpost_p = wsp + WPOST_OFF;

    // ---------------- phase 0: wave-local staging ----------------
    // lat gather: 128 (cell,dir) pairs, 2 per lane
    const int r1 = lane >> 3, d1 = lane & 7;
    const int r2 = r1 + 8,    d2 = d1;               // pair 1 = lane+64
    int src1 = coming_from[(size_t)d1 * NCELL + cbase + r1];
    int src2 = coming_from[(size_t)d2 * NCELL + cbase + r2];
    const float4* lp1 = (const float4*)(lat_prev + (size_t)src1 * 128 + d1 * 16);
    const float4* lp2 = (const float4*)(lat_prev + (size_t)src2 * 128 + d2 * 16);
    float4 ga0 = lp1[0], ga1 = lp1[1], ga2 = lp1[2], ga3 = lp1[3];
    float4 gb0 = lp2[0], gb1 = lp2[1], gb2 = lp2[2], gb3 = lp2[3];
    // dyn: 128 floats, 2 per lane
    const int dr = lane >> 2, dc = (lane & 3) * 2;
    float2 dv = *(const float2*)(dyn_in + (size_t)(cbase + dr) * 8 + dc);
    // h: 1024 floats, 16 per lane -- parked in regs until after GEMM1
    const int hr = lane >> 2, hq = lane & 3;
    const float4* hp = (const float4*)(lstm_h + (size_t)(cbase + hr) * 64 + hq * 16);
    float4 h0 = hp[0], h1 = hp[1], h2 = hp[2], h3 = hp[3];
    // b_pre for this lane's 4 output cols
    float bp0 = b_pre[lr], bp1 = b_pre[16 + lr], bp2v = b_pre[32 + lr], bp3 = b_pre[48 + lr];

    // X writes
    *(int*)(rowp + dr * ROWB + 2 * dc) = pack2(dv.x, dv.y);
    {
        int4 wa0{pack2(ga0.x, ga0.y), pack2(ga0.z, ga0.w), pack2(ga1.x, ga1.y), pack2(ga1.z, ga1.w)};
        int4 wa1{pack2(ga2.x, ga2.y), pack2(ga2.z, ga2.w), pack2(ga3.x, ga3.y), pack2(ga3.z, ga3.w)};
        char* dsta = rowp + r1 * ROWB + 16 + 32 * d1;
        *(int4*)dsta        = wa0;
        *(int4*)(dsta + 16) = wa1;
        int4 wb0{pack2(gb0.x, gb0.y), pack2(gb0.z, gb0.w), pack2(gb1.x, gb1.y), pack2(gb1.z, gb1.w)};
        int4 wb1{pack2(gb2.x, gb2.y), pack2(gb2.z, gb2.w), pack2(gb3.x, gb3.y), pack2(gb3.z, gb3.w)};
        char* dstb = rowp + r2 * ROWB + 16 + 32 * d2;
        *(int4*)dstb        = wb0;
        *(int4*)(dstb + 16) = wb1;
    }
    if (lane < 16) {                                  // zero pad cols 136..159
        int4 z{0, 0, 0, 0};
        char* pz = rowp + lane * ROWB;
        *(int4*)(pz + 272) = z;
        *(int4*)(pz + 288) = z;
        *(int4*)(pz + 304) = z;
    }

    // ---------------- GEMM1: X[16x160] @ Wpre'[160x64] -> pre (regs) ----------------
    f32x4 acc1[4];
#pragma unroll
    for (int n = 0; n < 4; ++n) acc1[n] = (f32x4){0.f, 0.f, 0.f, 0.f};
#pragma unroll
    for (int s = 0; s < 5; ++s) {
        bf16x8 a = *(const bf16x8*)(rowp + lr * ROWB + s * 64 + lg * 16);
#pragma unroll
        for (int n = 0; n < 4; ++n) {
            bf16x8 b = *(const bf16x8*)(wpre_p + ((s * 64 + n * 16 + lr) * 32 + lg * 8));
            acc1[n] = __builtin_amdgcn_mfma_f32_16x16x32_bf16(a, b, acc1[n], 0, 0, 0);
        }
    }

    // pre -> LDS bytes 0..127 (value-dependent on X reads, so ordered); then fence + h
    {
        float bps[4] = {bp0, bp1, bp2v, bp3};
#pragma unroll
        for (int n = 0; n < 4; ++n)
#pragma unroll
            for (int rr = 0; rr < 4; ++rr) {
                int row = lg * 4 + rr;
                float pv = fast_tanh(acc1[n][rr] + bps[n]);
                *(unsigned short*)(rowp + row * ROWB + 2 * (n * 16 + lr)) = f2bf(pv);
            }
    }
    // fence: X reads (bytes 128..255) must retire before h overwrites them
    asm volatile("s_waitcnt lgkmcnt(0)" ::: "memory");
    {
        int4 w0{pack2(h0.x, h0.y), pack2(h0.z, h0.w), pack2(h1.x, h1.y), pack2(h1.z, h1.w)};
        int4 w1{pack2(h2.x, h2.y), pack2(h2.z, h2.w), pack2(h3.x, h3.y), pack2(h3.z, h3.w)};
        char* dsth = rowp + hr * ROWB + 128 + 32 * hq;
        *(int4*)dsth        = w0;
        *(int4*)(dsth + 16) = w1;
    }
    asm volatile("s_waitcnt lgkmcnt(0)" ::: "memory");

    // ---------------- GEMM2: [pre||h][16x128] @ W2'[128x256] + LSTM ----------------
    bf16x8 a2[4];
#pragma unroll
    for (int s = 0; s < 4; ++s)
        a2[s] = *(const bf16x8*)(rowp + lr * ROWB + s * 64 + lg * 16);

    float c_cur[4], c_nxt[4];
#pragma unroll
    for (int rr = 0; rr < 4; ++rr)
        c_cur[rr] = lstm_c[(size_t)(cbase + lg * 4 + rr) * 64 + lr];

#pragma unroll
    for (int n0 = 0; n0 < 4; ++n0) {
        f32x4 acc[4];
#pragma unroll
        for (int j = 0; j < 4; ++j) acc[j] = (f32x4){0.f, 0.f, 0.f, 0.f};
#pragma unroll
        for (int s = 0; s < 4; ++s) {
#pragma unroll
            for (int j = 0; j < 4; ++j) {
                bf16x8 b = *(const bf16x8*)(w2_p +
                             ((s * 256 + j * 64 + n0 * 16 + lr) * 32 + lg * 8));
                acc[j] = __builtin_amdgcn_mfma_f32_16x16x32_bf16(a2[s], b, acc[j], 0, 0, 0);
            }
        }
        if (n0 < 3) {                                  // prefetch next hid-group's c
            int hid2 = (n0 + 1) * 16 + lr;
#pragma unroll
            for (int rr = 0; rr < 4; ++rr)
                c_nxt[rr] = lstm_c[(size_t)(cbase + lg * 4 + rr) * 64 + hid2];
        }
        const int hid = n0 * 16 + lr;
        float bi  = b_lstm[hid],       bfv = b_lstm[64 + hid];
        float bg  = b_lstm[128 + hid], bo  = b_lstm[192 + hid];
#pragma unroll
        for (int rr = 0; rr < 4; ++rr) {
            int row = lg * 4 + rr;
            size_t cell = (size_t)(cbase + row);
            float iv = fast_sigmoid(acc[0][rr] + bi);
            float fv = fast_sigmoid(acc[1][rr] + bfv);
            float gv = fast_tanh(acc[2][rr] + bg);
            float ov = fast_sigmoid(acc[3][rr] + bo);
            float cn = fv * c_cur[rr] + iv * gv;
            float hn = ov * fast_tanh(cn);
            out[OUT_C + cell * 64 + hid] = cn;
            out[OUT_H + cell * 64 + hid] = hn;
            // hn -> LDS bytes 0..127 (pre region dead: pre cached in a2 regs)
            *(unsigned short*)(rowp + row * ROWB + 2 * hid) = f2bf(hn);
        }
        if (n0 < 3) {
#pragma unroll
            for (int rr = 0; rr < 4; ++rr) c_cur[rr] = c_nxt[rr];
        }
    }
    asm volatile("s_waitcnt lgkmcnt(0)" ::: "memory");

    // ---------------- GEMM3: hn[16x64] @ Wpost'[64x144], tanh -> dyn/lat ----------------
    bf16x8 a3[2];
    a3[0] = *(const bf16x8*)(rowp + lr * ROWB + 0 + lg * 16);
    a3[1] = *(const bf16x8*)(rowp + lr * ROWB + 64 + lg * 16);
#pragma unroll
    for (int grp = 0; grp < 3; ++grp) {
        f32x4 acc[3];
#pragma unroll
        for (int q = 0; q < 3; ++q) acc[q] = (f32x4){0.f, 0.f, 0.f, 0.f};
#pragma unroll
        for (int s = 0; s < 2; ++s) {
#pragma unroll
            for (int q = 0; q < 3; ++q) {
                int n = grp * 3 + q;
                bf16x8 b = *(const bf16x8*)(wpost_p + ((s * 144 + n * 16 + lr) * 32 + lg * 8));
                acc[q] = __builtin_amdgcn_mfma_f32_16x16x32_bf16(a3[s], b, acc[q], 0, 0, 0);
            }
        }
#pragma unroll
        for (int q = 0; q < 3; ++q) {
            int n   = grp * 3 + q;
            int col = n * 16 + lr;
            if (col < DIN) {
                float bpv = b_post[col];
#pragma unroll
                for (int rr = 0; rr < 4; ++rr) {
                    int row = lg * 4 + rr;
                    size_t cell = (size_t)(cbase + row);
                    float pv = fast_tanh(acc[q][rr] + bpv);
                    if (col < 8)
                        out[cell * 8 + col] = pv;
                    else
                        out[OUT_LAT + cell * 128 + (col - 8)] = pv;
                }
            }
        }
    }
}

extern "C" void kernel_launch(void* const* d_in, const int* in_sizes, int n_in,
                              void* d_out, int out_size, void* d_ws, size_t ws_size,
                              hipStream_t stream) {
    const float* dyn_in      = (const float*)d_in[0];
    const float* lat_prev    = (const float*)d_in[1];
    const float* lstm_c      = (const float*)d_in[2];
    const float* lstm_h      = (const float*)d_in[3];
    const int*   coming_from = (const int*)d_in[5];
    const float* W_pre  = (const float*)d_in[7];
    const float* b_pre  = (const float*)d_in[8];
    const float* W_ih   = (const float*)d_in[9];
    const float* W_hh   = (const float*)d_in[10];
    const float* b_lstm = (const float*)d_in[11];
    const float* W_post = (const float*)d_in[12];
    const float* b_post = (const float*)d_in[13];
    unsigned short* wsp = (unsigned short*)d_ws;

    prep_weights<<<(WTOTAL + 255) / 256, 256, 0, stream>>>(W_pre, W_ih, W_hh, W_post, wsp);
    knet_fused<<<NCELL / 64, 256, 0, stream>>>(dyn_in, lat_prev, lstm_c, lstm_h, coming_from,
                                               wsp, b_pre, b_lstm, b_post, (float*)d_out);
}

// Round 3
// 389.042 us; speedup vs baseline: 1.0610x; 1.0610x over previous
//
#include <hip/hip_runtime.h>
#include <stdint.h>

#define NCELL (512 * 512)
#define DIN   136

// output layout (flat f32, concat in return order)
#define OUT_LAT 2097152ull                 // N*8
#define OUT_C   35651584ull                // OUT_LAT + N*128
#define OUT_H   52428800ull                // OUT_C + N*64

// packed-weight offsets in d_ws (bf16 elements)
#define WPRE_OFF  0        // [5][64][32]   = 10240
#define W2_OFF    10240    // [4][256][32]  = 32768
#define WPOST_OFF 43008    // [2][144][32]  = 9216
#define WTOTAL    52224

// LDS row stride: 400B (100 dwords; 100 mod 32 = 4 -> b128 reads stay 2-way-free)
// row layout: [0..319] X cols 0..159 (GEMM1); after barrier: [0..127] pre,
// [128..255] h; [272..399] hn (overwrites dead X pad cols 136..159 + spare)
#define ROWB 400

typedef __bf16 bf16x8 __attribute__((ext_vector_type(8)));
typedef float  f32x4  __attribute__((ext_vector_type(4)));

__device__ __forceinline__ unsigned short f2bf(float f) {
    unsigned int u = __float_as_uint(f);
    u += 0x7FFF + ((u >> 16) & 1);          // round-to-nearest-even
    return (unsigned short)(u >> 16);
}
__device__ __forceinline__ int pack2(float a, float b) {
    return (int)f2bf(a) | ((int)f2bf(b) << 16);
}
__device__ __forceinline__ float fast_sigmoid(float x) {
    return __builtin_amdgcn_rcpf(1.f + __expf(-x));
}
__device__ __forceinline__ float fast_tanh(float x) {
    float e = __expf(2.f * x);              // inf-safe: rcp(inf)=0 -> 1; e->0 -> -1
    return 1.f - 2.f * __builtin_amdgcn_rcpf(e + 1.f);
}

// Repack weights to bf16, MFMA-B-fragment-friendly: [K/32][Ncol][32]
__global__ void prep_weights(const float* __restrict__ Wpre,
                             const float* __restrict__ Wih,
                             const float* __restrict__ Whh,
                             const float* __restrict__ Wpost,
                             unsigned short* __restrict__ ws) {
    int i = blockIdx.x * 256 + threadIdx.x;
    if (i < 10240) {                                   // Wpre' : K 136->160 pad, N=64
        int k = i & 31, n = (i >> 5) & 63, s = i >> 11;
        int K = s * 32 + k;
        ws[i] = (K < DIN) ? f2bf(Wpre[K * 64 + n]) : (unsigned short)0;
    } else if (i < 43008) {                            // W2'   : K=128 (ih||hh), N=256
        int j = i - 10240;
        int k = j & 31, n = (j >> 5) & 255, s = j >> 13;
        int K = s * 32 + k;
        float v = (K < 64) ? Wih[K * 256 + n] : Whh[(K - 64) * 256 + n];
        ws[i] = f2bf(v);
    } else if (i < WTOTAL) {                           // Wpost': K=64, N 136->144 pad
        int j = i - 43008;
        int k = j & 31;
        int t = j >> 5;
        int n = t % 144;
        int s = t / 144;
        int K = s * 32 + k;
        ws[i] = (n < DIN) ? f2bf(Wpost[K * DIN + n]) : (unsigned short)0;
    }
}

// Cooperative fused kernel: block = 256 threads (4 waves) = 64 cells.
// GEMM1/2/3 N-split across waves (weight loads amortized over 64 cells).
// GEMM2 done in two passes (i,g) then (f,o) to halve accumulator pressure.
__global__ __launch_bounds__(256, 6) void knet_fused(
    const float* __restrict__ dyn_in,
    const float* __restrict__ lat_prev,
    const float* __restrict__ lstm_c,
    const float* __restrict__ lstm_h,
    const int*   __restrict__ coming_from,
    const unsigned short* __restrict__ wsp,
    const float* __restrict__ b_pre,
    const float* __restrict__ b_lstm,
    const float* __restrict__ b_post,
    float* __restrict__ out) {
    __shared__ __align__(16) char Ls[64 * ROWB];

    const int t  = threadIdx.x;
    const int p0 = blockIdx.x * 64;
    const unsigned short* wpre_p  = wsp + WPRE_OFF;
    const unsigned short* w2_p    = wsp + W2_OFF;
    const unsigned short* wpost_p = wsp + WPOST_OFF;

    // ---------------- phase 0: staging ----------------
    // h: 16 floats/thread, pack to 8 ints, hold until after GEMM1 (its LDS
    // region holds live X during GEMM1)
    const int hr = t >> 2, hq = t & 3;
    int hpk[8];
    {
        const float4* hp = (const float4*)(lstm_h + (size_t)(p0 + hr) * 64 + hq * 16);
        float4 v0 = hp[0], v1 = hp[1], v2 = hp[2], v3 = hp[3];
        hpk[0] = pack2(v0.x, v0.y); hpk[1] = pack2(v0.z, v0.w);
        hpk[2] = pack2(v1.x, v1.y); hpk[3] = pack2(v1.z, v1.w);
        hpk[4] = pack2(v2.x, v2.y); hpk[5] = pack2(v2.z, v2.w);
        hpk[6] = pack2(v3.x, v3.y); hpk[7] = pack2(v3.z, v3.w);
    }
    if (t < 128) {  // dyn_in -> X cols 0..7
        int r = t >> 1, c = (t & 1) * 4;
        float4 v = *(const float4*)(dyn_in + (size_t)(p0 + r) * 8 + c);
        int2 wv{pack2(v.x, v.y), pack2(v.z, v.w)};
        *(int2*)(Ls + r * ROWB + c * 2) = wv;
    }
    {   // zero pad X cols 136..159 (48B at bytes 272..319)
        int r = t >> 2, q = t & 3;
        if (q < 3) *(int4*)(Ls + r * ROWB + 272 + 16 * q) = int4{0, 0, 0, 0};
    }
#pragma unroll
    for (int qq = 0; qq < 2; ++qq) {  // lat gather -> X cols 8..135
        int q = t + qq * 256;
        int r = q >> 3, d = q & 7;
        int src = coming_from[(size_t)d * NCELL + p0 + r];
        const float4* lp = (const float4*)(lat_prev + (size_t)src * 128 + d * 16);
        float4 v0 = lp[0], v1 = lp[1], v2 = lp[2], v3 = lp[3];
        char* dst = Ls + r * ROWB + 16 + 32 * d;
        int4 w0{pack2(v0.x, v0.y), pack2(v0.z, v0.w), pack2(v1.x, v1.y), pack2(v1.z, v1.w)};
        int4 w1{pack2(v2.x, v2.y), pack2(v2.z, v2.w), pack2(v3.x, v3.y), pack2(v3.z, v3.w)};
        *(int4*)dst        = w0;
        *(int4*)(dst + 16) = w1;
    }
    __syncthreads();

    const int lane = t & 63;
    const int w    = t >> 6;     // wave id = N-tile owner
    const int lr   = lane & 15;
    const int lg   = lane >> 4;

    // ---------------- GEMM1: X[64x160] @ Wpre'[160x64] -> pre (wave owns N-tile w)
    unsigned short prebf[16];
    {
        f32x4 acc1[4];
#pragma unroll
        for (int m = 0; m < 4; ++m) acc1[m] = (f32x4){0.f, 0.f, 0.f, 0.f};
#pragma unroll
        for (int s = 0; s < 5; ++s) {
            bf16x8 b = *(const bf16x8*)(wpre_p + ((s * 64 + w * 16 + lr) * 32 + lg * 8));
#pragma unroll
            for (int m = 0; m < 4; ++m) {
                bf16x8 a = *(const bf16x8*)(Ls + (m * 16 + lr) * ROWB + s * 64 + lg * 16);
                acc1[m] = __builtin_amdgcn_mfma_f32_16x16x32_bf16(a, b, acc1[m], 0, 0, 0);
            }
        }
        float bp = b_pre[w * 16 + lr];
#pragma unroll
        for (int m = 0; m < 4; ++m)
#pragma unroll
            for (int rr = 0; rr < 4; ++rr)
                prebf[m * 4 + rr] = f2bf(fast_tanh(acc1[m][rr] + bp));
    }
    __syncthreads();   // all GEMM1 X-reads done -> safe to overwrite bytes 0..255

    {   // pre -> bytes 0..127 (col w*16+lr, 16 rows)
        int colb = (w * 16 + lr) * 2;
#pragma unroll
        for (int m = 0; m < 4; ++m)
#pragma unroll
            for (int rr = 0; rr < 4; ++rr) {
                int row = m * 16 + lg * 4 + rr;
                *(unsigned short*)(Ls + row * ROWB + colb) = prebf[m * 4 + rr];
            }
        // h -> bytes 128..255
        char* dsth = Ls + hr * ROWB + 128 + 32 * hq;
        *(int4*)dsth        = int4{hpk[0], hpk[1], hpk[2], hpk[3]};
        *(int4*)(dsth + 16) = int4{hpk[4], hpk[5], hpk[6], hpk[7]};
    }
    __syncthreads();   // pre/h visible

    // ---------------- GEMM2: [pre||h][64x128] @ W2'[128x256], two passes + LSTM
    {
        bf16x8 a2[4];
#pragma unroll
        for (int s = 0; s < 4; ++s)
            a2[s] = *(const bf16x8*)(Ls + (0 * 16 + lr) * ROWB + s * 64 + lg * 16);
        // note: a-frags per m-tile loaded inside the s-loops below; a2 caches m=0? No:
        // load per (m,s) fresh each pass to keep live-range small.

        const int hid = w * 16 + lr;
        const float bi = b_lstm[hid],       bg = b_lstm[128 + hid];
        const float bf = b_lstm[64 + hid],  bo = b_lstm[192 + hid];

        // ---- pass A: gates i (tile w), g (tile w+8) ----
        f32x4 acc[4][2];
#pragma unroll
        for (int m = 0; m < 4; ++m)
#pragma unroll
            for (int j = 0; j < 2; ++j) acc[m][j] = (f32x4){0.f, 0.f, 0.f, 0.f};
#pragma unroll
        for (int s = 0; s < 4; ++s) {
            bf16x8 b0 = *(const bf16x8*)(w2_p + ((s * 256 + (w)      * 16 + lr) * 32 + lg * 8));
            bf16x8 b1 = *(const bf16x8*)(w2_p + ((s * 256 + (w + 8)  * 16 + lr) * 32 + lg * 8));
#pragma unroll
            for (int m = 0; m < 4; ++m) {
                bf16x8 a = *(const bf16x8*)(Ls + (m * 16 + lr) * ROWB + s * 64 + lg * 16);
                acc[m][0] = __builtin_amdgcn_mfma_f32_16x16x32_bf16(a, b0, acc[m][0], 0, 0, 0);
                acc[m][1] = __builtin_amdgcn_mfma_f32_16x16x32_bf16(a, b1, acc[m][1], 0, 0, 0);
            }
        }
        float ig[16];
#pragma unroll
        for (int m = 0; m < 4; ++m)
#pragma unroll
            for (int rr = 0; rr < 4; ++rr)
                ig[m * 4 + rr] = fast_sigmoid(acc[m][0][rr] + bi) *
                                 fast_tanh(acc[m][1][rr] + bg);

        // prefetch c for this hid-block (coalesced 64B segments)
        float cpf[16];
#pragma unroll
        for (int m = 0; m < 4; ++m)
#pragma unroll
            for (int rr = 0; rr < 4; ++rr)
                cpf[m * 4 + rr] =
                    lstm_c[(size_t)(p0 + m * 16 + lg * 4 + rr) * 64 + hid];

        // ---- pass B: gates f (tile w+4), o (tile w+12) ----
#pragma unroll
        for (int m = 0; m < 4; ++m)
#pragma unroll
            for (int j = 0; j < 2; ++j) acc[m][j] = (f32x4){0.f, 0.f, 0.f, 0.f};
#pragma unroll
        for (int s = 0; s < 4; ++s) {
            bf16x8 b0 = *(const bf16x8*)(w2_p + ((s * 256 + (w + 4)  * 16 + lr) * 32 + lg * 8));
            bf16x8 b1 = *(const bf16x8*)(w2_p + ((s * 256 + (w + 12) * 16 + lr) * 32 + lg * 8));
#pragma unroll
            for (int m = 0; m < 4; ++m) {
                bf16x8 a = *(const bf16x8*)(Ls + (m * 16 + lr) * ROWB + s * 64 + lg * 16);
                acc[m][0] = __builtin_amdgcn_mfma_f32_16x16x32_bf16(a, b0, acc[m][0], 0, 0, 0);
                acc[m][1] = __builtin_amdgcn_mfma_f32_16x16x32_bf16(a, b1, acc[m][1], 0, 0, 0);
            }
        }
        // ---- LSTM pointwise + outputs ----
#pragma unroll
        for (int m = 0; m < 4; ++m)
#pragma unroll
            for (int rr = 0; rr < 4; ++rr) {
                int row = m * 16 + lg * 4 + rr;
                size_t cell = (size_t)(p0 + row);
                float fv = fast_sigmoid(acc[m][0][rr] + bf);
                float ov = fast_sigmoid(acc[m][1][rr] + bo);
                float cn = fv * cpf[m * 4 + rr] + ig[m * 4 + rr];
                float hn = ov * fast_tanh(cn);
                out[OUT_C + cell * 64 + hid] = cn;
                out[OUT_H + cell * 64 + hid] = hn;
                // hn -> bytes 272..399 (dead X-pad region: no WAR hazard)
                *(unsigned short*)(Ls + row * ROWB + 272 + 2 * hid) = f2bf(hn);
            }
        (void)a2;
    }
    __syncthreads();   // hn visible

    // ---------------- GEMM3: hn[64x64] @ Wpost'[64x144], tanh -> dyn/lat ----------------
    {
        f32x4 acc3[4][3];
#pragma unroll
        for (int m = 0; m < 4; ++m)
#pragma unroll
            for (int jj = 0; jj < 3; ++jj) acc3[m][jj] = (f32x4){0.f, 0.f, 0.f, 0.f};
        const int ntiles = (w == 0) ? 3 : 2;  // tiles {w, w+4, (w==0: 8)} cover 0..8
#pragma unroll
        for (int s = 0; s < 2; ++s) {
            bf16x8 a[4];
#pragma unroll
            for (int m = 0; m < 4; ++m)
                a[m] = *(const bf16x8*)(Ls + (m * 16 + lr) * ROWB + 272 + s * 64 + lg * 16);
#pragma unroll
            for (int jj = 0; jj < 3; ++jj) {
                if (jj < ntiles) {
                    int n = w + 4 * jj;
                    bf16x8 b =
                        *(const bf16x8*)(wpost_p + ((s * 144 + n * 16 + lr) * 32 + lg * 8));
#pragma unroll
                    for (int m = 0; m < 4; ++m)
                        acc3[m][jj] = __builtin_amdgcn_mfma_f32_16x16x32_bf16(a[m], b,
                                                                              acc3[m][jj],
                                                                              0, 0, 0);
                }
            }
        }
#pragma unroll
        for (int jj = 0; jj < 3; ++jj) {
            if (jj < ntiles) {
                int n   = w + 4 * jj;
                int col = n * 16 + lr;
                if (col < DIN) {
                    float bpv = b_post[col];
#pragma unroll
                    for (int m = 0; m < 4; ++m)
#pragma unroll
                        for (int rr = 0; rr < 4; ++rr) {
                            int row = m * 16 + lg * 4 + rr;
                            size_t cell = (size_t)(p0 + row);
                            float pv = fast_tanh(acc3[m][jj][rr] + bpv);
                            if (col < 8)
                                out[cell * 8 + col] = pv;
                            else
                                out[OUT_LAT + cell * 128 + (col - 8)] = pv;
                        }
                }
            }
        }
    }
}

extern "C" void kernel_launch(void* const* d_in, const int* in_sizes, int n_in,
                              void* d_out, int out_size, void* d_ws, size_t ws_size,
                              hipStream_t stream) {
    const float* dyn_in      = (const float*)d_in[0];
    const float* lat_prev    = (const float*)d_in[1];
    const float* lstm_c      = (const float*)d_in[2];
    const float* lstm_h      = (const float*)d_in[3];
    const int*   coming_from = (const int*)d_in[5];
    const float* W_pre  = (const float*)d_in[7];
    const float* b_pre  = (const float*)d_in[8];
    const float* W_ih   = (const float*)d_in[9];
    const float* W_hh   = (const float*)d_in[10];
    const float* b_lstm = (const float*)d_in[11];
    const float* W_post = (const float*)d_in[12];
    const float* b_post = (const float*)d_in[13];
    unsigned short* wsp = (unsigned short*)d_ws;

    prep_weights<<<(WTOTAL + 255) / 256, 256, 0, stream>>>(W_pre, W_ih, W_hh, W_post, wsp);
    knet_fused<<<NCELL / 64, 256, 0, stream>>>(dyn_in, lat_prev, lstm_c, lstm_h, coming_from,
                                               wsp, b_pre, b_lstm, b_post, (float*)d_out);
}

// Round 4
// 181.362 us; speedup vs baseline: 2.2759x; 2.1451x over previous
//
#include <hip/hip_runtime.h>
#include <stdint.h>

#define NCELL (512 * 512)
#define DIN   136

// output layout (flat f32, concat in return order)
#define OUT_LAT 2097152ull                 // N*8
#define OUT_C   35651584ull                // OUT_LAT + N*128
#define OUT_H   52428800ull                // OUT_C + N*64

// packed-weight offsets in d_ws (bf16 elements)
#define WPRE_OFF  0        // [5][64][32]   = 10240
#define W2_OFF    10240    // [4][256][32]  = 32768
#define WPOST_OFF 43008    // [2][160][32]  = 10240 ; n' 0..7 = dyn, 8..31 = zero pad,
                           //                 32..159 = lat cols 0..127 (line-aligned tiles)
#define WTOTAL    53248

#define ROWB 336           // LDS bytes per cell-row (21*16; 5r mod 8 spreads bank slots)

typedef __bf16 bf16x8 __attribute__((ext_vector_type(8)));
typedef float  f32x4  __attribute__((ext_vector_type(4)));

__device__ __forceinline__ unsigned short f2bf(float f) {
    unsigned int u = __float_as_uint(f);
    u += 0x7FFF + ((u >> 16) & 1);          // round-to-nearest-even
    return (unsigned short)(u >> 16);
}
__device__ __forceinline__ int pack2(float a, float b) {
    return (int)f2bf(a) | ((int)f2bf(b) << 16);
}
__device__ __forceinline__ float fast_sigmoid(float x) {
    return __builtin_amdgcn_rcpf(1.f + __expf(-x));
}
__device__ __forceinline__ float fast_tanh(float x) {
    float e = __expf(2.f * x);              // inf-safe: rcp(inf)=0 -> 1; e->0 -> -1
    return 1.f - 2.f * __builtin_amdgcn_rcpf(e + 1.f);
}
__device__ __forceinline__ float bf2f_lo(int u) {
    return __uint_as_float((unsigned)u << 16);
}
__device__ __forceinline__ float bf2f_hi(int u) {
    return __uint_as_float((unsigned)u & 0xffff0000u);
}

// Repack weights to bf16, MFMA-B-fragment-friendly: [K/32][Ncol][32]
__global__ void prep_weights(const float* __restrict__ Wpre,
                             const float* __restrict__ Wih,
                             const float* __restrict__ Whh,
                             const float* __restrict__ Wpost,
                             unsigned short* __restrict__ ws) {
    int i = blockIdx.x * 256 + threadIdx.x;
    if (i < 10240) {                                   // Wpre' : K 136->160 pad, N=64
        int k = i & 31, n = (i >> 5) & 63, s = i >> 11;
        int K = s * 32 + k;
        ws[i] = (K < DIN) ? f2bf(Wpre[K * 64 + n]) : (unsigned short)0;
    } else if (i < 43008) {                            // W2'   : K=128 (ih||hh), N=256
        int j = i - 10240;
        int k = j & 31, n = (j >> 5) & 255, s = j >> 13;
        int K = s * 32 + k;
        float v = (K < 64) ? Wih[K * 256 + n] : Whh[(K - 64) * 256 + n];
        ws[i] = f2bf(v);
    } else if (i < WTOTAL) {                           // Wpost2: [2][160][32], line-aligned
        int j = i - 43008;
        int k = j & 31;
        int t2 = j >> 5;            // 0..319
        int n = t2 % 160;
        int s = t2 / 160;
        int K = s * 32 + k;         // 0..63
        float v = 0.f;
        if (n < 8)        v = Wpost[K * DIN + n];          // dyn cols
        else if (n >= 32) v = Wpost[K * DIN + (n - 24)];   // lat cols 0..127
        ws[i] = f2bf(v);
    }
}

// Cooperative fused kernel: block = 256 threads (4 waves) = 64 cells.
// Identical to the 195us R1 structure except all global WRITES are
// full-128B-line single-writer (c/h via LDS-staged coop stores; lat/dyn via
// line-aligned Wpost tiling).
__global__ __launch_bounds__(256, 4) void knet_fused(
    const float* __restrict__ dyn_in,
    const float* __restrict__ lat_prev,
    const float* __restrict__ lstm_c,
    const float* __restrict__ lstm_h,
    const int*   __restrict__ coming_from,
    const unsigned short* __restrict__ wsp,
    const float* __restrict__ b_pre,
    const float* __restrict__ b_lstm,
    const float* __restrict__ b_post,
    float* __restrict__ out) {
    // Xs: [64][336B] : X bf16 cols 0..159 during GEMM1 (272..319 zero pad).
    //     During LSTM epilogue (Xs dead): hn bf16 -> bytes 0..127 (XOR swz),
    //     cn bf16 -> bytes 128..255 (same swz). Read by GEMM3 + coop stores.
    __shared__ __align__(16) char Xs[64 * ROWB];
    // A2s: [64][128] bf16 (cols 0-63 = pre, 64-127 = h_prev), XOR-swizzled rows
    __shared__ __align__(16) unsigned short A2s[64 * 128];

    const int t  = threadIdx.x;
    const int p0 = blockIdx.x * 64;
    const unsigned short* wpre_p  = wsp + WPRE_OFF;
    const unsigned short* w2_p    = wsp + W2_OFF;
    const unsigned short* wpost_p = wsp + WPOST_OFF;

    // ---------------- phase 0: staging ----------------
    {
        // h_prev -> A2s cols 64..127 (bf16, swizzled). 16 values/thread.
        int r = t >> 2, q = t & 3;
        int sw = (r & 7) << 4;
        const float4* hp = (const float4*)(lstm_h + (size_t)(p0 + r) * 64 + q * 16);
        float4 v0 = hp[0], v1 = hp[1], v2 = hp[2], v3 = hp[3];
        char* rowp = (char*)A2s + r * 256;
        int4 w0{pack2(v0.x, v0.y), pack2(v0.z, v0.w), pack2(v1.x, v1.y), pack2(v1.z, v1.w)};
        int4 w1{pack2(v2.x, v2.y), pack2(v2.z, v2.w), pack2(v3.x, v3.y), pack2(v3.z, v3.w)};
        *(int4*)(rowp + ((128 + 32 * q) ^ sw))      = w0;
        *(int4*)(rowp + ((128 + 32 * q + 16) ^ sw)) = w1;

        // zero pad X cols 136..159 (bytes 272..319)
        if (q < 3) *(int4*)(Xs + r * ROWB + 272 + 16 * q) = int4{0, 0, 0, 0};
    }
    if (t < 128) {  // dyn_in -> X cols 0..7
        int r = t >> 1, c = (t & 1) * 4;
        float4 v = *(const float4*)(dyn_in + (size_t)(p0 + r) * 8 + c);
        int2 wv{pack2(v.x, v.y), pack2(v.z, v.w)};
        *(int2*)(Xs + r * ROWB + c * 2) = wv;
    }
#pragma unroll
    for (int qq = 0; qq < 2; ++qq) {  // lat gather -> X cols 8..135
        int q = t + qq * 256;
        int r = q >> 3, d = q & 7;
        int src = coming_from[(size_t)d * NCELL + p0 + r];
        const float4* lp = (const float4*)(lat_prev + (size_t)src * 128 + d * 16);
        float4 v0 = lp[0], v1 = lp[1], v2 = lp[2], v3 = lp[3];
        char* dst = Xs + r * ROWB + 16 + 32 * d;
        int4 w0{pack2(v0.x, v0.y), pack2(v0.z, v0.w), pack2(v1.x, v1.y), pack2(v1.z, v1.w)};
        int4 w1{pack2(v2.x, v2.y), pack2(v2.z, v2.w), pack2(v3.x, v3.y), pack2(v3.z, v3.w)};
        *(int4*)dst        = w0;
        *(int4*)(dst + 16) = w1;
    }
    __syncthreads();

    const int lane = t & 63;
    const int w    = t >> 6;     // wave id = N-tile owner
    const int lr   = lane & 15;
    const int lg   = lane >> 4;

    // ---------------- GEMM1: X[64x160] @ Wpre'[160x64] -> pre -> A2s cols 0..63
    {
        f32x4 acc1[4];
#pragma unroll
        for (int m = 0; m < 4; ++m) acc1[m] = (f32x4){0.f, 0.f, 0.f, 0.f};
#pragma unroll
        for (int s = 0; s < 5; ++s) {
            bf16x8 b = *(const bf16x8*)(wpre_p + ((s * 64 + w * 16 + lr) * 32 + lg * 8));
#pragma unroll
            for (int m = 0; m < 4; ++m) {
                bf16x8 a = *(const bf16x8*)(Xs + (m * 16 + lr) * ROWB + s * 64 + lg * 16);
                acc1[m] = __builtin_amdgcn_mfma_f32_16x16x32_bf16(a, b, acc1[m], 0, 0, 0);
            }
        }
        float bp = b_pre[w * 16 + lr];
        int colb = (w * 16 + lr) * 2;
#pragma unroll
        for (int m = 0; m < 4; ++m)
#pragma unroll
            for (int rr = 0; rr < 4; ++rr) {
                int row = m * 16 + lg * 4 + rr;
                float pv = fast_tanh(acc1[m][rr] + bp);
                *(unsigned short*)((char*)A2s + row * 256 + (colb ^ ((row & 7) << 4))) =
                    f2bf(pv);
            }
    }
    __syncthreads();   // pre/h visible (also: all GEMM1 X-reads retired)

    // ---------------- GEMM2: [pre||h][64x128] @ W2'[128x256] + LSTM ----------------
    {
        const int hid = w * 16 + lr;
        // prefetch c_old early (hide latency under MFMAs)
        float cpf[16];
#pragma unroll
        for (int m = 0; m < 4; ++m)
#pragma unroll
            for (int rr = 0; rr < 4; ++rr)
                cpf[m * 4 + rr] =
                    lstm_c[(size_t)(p0 + m * 16 + lg * 4 + rr) * 64 + hid];

        f32x4 acc2[4][4];  // [m][j], gate tile n = w + 4*j  (j: 0=i,1=f,2=g,3=o)
#pragma unroll
        for (int m = 0; m < 4; ++m)
#pragma unroll
            for (int j = 0; j < 4; ++j) acc2[m][j] = (f32x4){0.f, 0.f, 0.f, 0.f};
#pragma unroll
        for (int s = 0; s < 4; ++s) {
            bf16x8 a[4];
#pragma unroll
            for (int m = 0; m < 4; ++m) {
                int row = m * 16 + lr;
                int cb  = (s * 32 + lg * 8) * 2;
                a[m] = *(const bf16x8*)((char*)A2s + row * 256 + (cb ^ ((row & 7) << 4)));
            }
#pragma unroll
            for (int j = 0; j < 4; ++j) {
                int n = w + 4 * j;
                bf16x8 b = *(const bf16x8*)(w2_p + ((s * 256 + n * 16 + lr) * 32 + lg * 8));
#pragma unroll
                for (int m = 0; m < 4; ++m)
                    acc2[m][j] =
                        __builtin_amdgcn_mfma_f32_16x16x32_bf16(a[m], b, acc2[m][j], 0, 0, 0);
            }
        }
        // LSTM pointwise: results -> LDS only (coop full-line stores after sync)
        float bi  = b_lstm[hid],       bfv = b_lstm[64 + hid];
        float bg  = b_lstm[128 + hid], bo  = b_lstm[192 + hid];
#pragma unroll
        for (int m = 0; m < 4; ++m)
#pragma unroll
            for (int rr = 0; rr < 4; ++rr) {
                int row = m * 16 + lg * 4 + rr;
                float iv = fast_sigmoid(acc2[m][0][rr] + bi);
                float fv = fast_sigmoid(acc2[m][1][rr] + bfv);
                float gv = fast_tanh(acc2[m][2][rr] + bg);
                float ov = fast_sigmoid(acc2[m][3][rr] + bo);
                float cn = fv * cpf[m * 4 + rr] + iv * gv;
                float hn = ov * fast_tanh(cn);
                int sw = (row & 7) << 4;
                char* rp = Xs + row * ROWB;       // Xs dead since GEMM1
                *(unsigned short*)(rp + ((2 * hid) ^ sw))       = f2bf(hn);
                *(unsigned short*)(rp + 128 + ((2 * hid) ^ sw)) = f2bf(cn);
            }
    }
    __syncthreads();   // hn/cn visible

    // ---------------- cooperative full-line c/h stores ----------------
    {
#pragma unroll
        for (int q = 0; q < 2; ++q) {
            int row = (t >> 3) + q * 32;
            int ch  = t & 7;
            const char* rp = Xs + row * ROWB;
            int off = (ch * 16) ^ ((row & 7) << 4);
            int4 hv = *(const int4*)(rp + off);
            int4 cv = *(const int4*)(rp + 128 + off);
            size_t rb = (size_t)(p0 + row) * 64 + ch * 8;
            float4 a0{bf2f_lo(cv.x), bf2f_hi(cv.x), bf2f_lo(cv.y), bf2f_hi(cv.y)};
            float4 a1{bf2f_lo(cv.z), bf2f_hi(cv.z), bf2f_lo(cv.w), bf2f_hi(cv.w)};
            *(float4*)(out + OUT_C + rb)     = a0;
            *(float4*)(out + OUT_C + rb + 4) = a1;
            float4 b0{bf2f_lo(hv.x), bf2f_hi(hv.x), bf2f_lo(hv.y), bf2f_hi(hv.y)};
            float4 b1{bf2f_lo(hv.z), bf2f_hi(hv.z), bf2f_lo(hv.w), bf2f_hi(hv.w)};
            *(float4*)(out + OUT_H + rb)     = b0;
            *(float4*)(out + OUT_H + rb + 4) = b1;
        }
    }

    // ---------------- GEMM3: hn[64x64] @ Wpost2'[64x160], tanh -> dyn/lat ----------
    // wave w owns tiles {2w+2, 2w+3} = lat 32-col line w of every row (single-writer
    // full lines); wave 0 additionally does the dyn tile (n'=0).
    {
        f32x4 acc3[4][3];
#pragma unroll
        for (int m = 0; m < 4; ++m)
#pragma unroll
            for (int jj = 0; jj < 3; ++jj) acc3[m][jj] = (f32x4){0.f, 0.f, 0.f, 0.f};
#pragma unroll
        for (int s = 0; s < 2; ++s) {
            bf16x8 a[4];
#pragma unroll
            for (int m = 0; m < 4; ++m) {
                int row = m * 16 + lr;
                a[m] = *(const bf16x8*)(Xs + row * ROWB +
                                        ((s * 64 + lg * 16) ^ ((lr & 7) << 4)));
            }
#pragma unroll
            for (int jj = 0; jj < 3; ++jj) {
                if (jj == 0 && w != 0) continue;
                int n = (jj == 0) ? 0 : (2 * w + 1 + jj);
                bf16x8 b =
                    *(const bf16x8*)(wpost_p + ((s * 160 + n * 16 + lr) * 32 + lg * 8));
#pragma unroll
                for (int m = 0; m < 4; ++m)
                    acc3[m][jj] = __builtin_amdgcn_mfma_f32_16x16x32_bf16(a[m], b,
                                                                          acc3[m][jj],
                                                                          0, 0, 0);
            }
        }
        // epilogue: per-lane scalar stores, but every 128B line single-writer now
        if (w == 0 && lr < 8) {                       // dyn tile
            float bpv = b_post[lr];
#pragma unroll
            for (int m = 0; m < 4; ++m)
#pragma unroll
                for (int rr = 0; rr < 4; ++rr) {
                    int row = m * 16 + lg * 4 + rr;
                    out[(size_t)(p0 + row) * 8 + lr] =
                        fast_tanh(acc3[m][0][rr] + bpv);
                }
        }
#pragma unroll
        for (int jj = 1; jj < 3; ++jj) {              // lat tiles (line w)
            int n = 2 * w + 1 + jj;
            int L = n * 16 + lr - 32;                 // lat col 0..127
            float bpv = b_post[L + 8];
#pragma unroll
            for (int m = 0; m < 4; ++m)
#pragma unroll
                for (int rr = 0; rr < 4; ++rr) {
                    int row = m * 16 + lg * 4 + rr;
                    out[OUT_LAT + (size_t)(p0 + row) * 128 + L] =
                        fast_tanh(acc3[m][jj][rr] + bpv);
                }
        }
    }
}

extern "C" void kernel_launch(void* const* d_in, const int* in_sizes, int n_in,
                              void* d_out, int out_size, void* d_ws, size_t ws_size,
                              hipStream_t stream) {
    const float* dyn_in      = (const float*)d_in[0];
    const float* lat_prev    = (const float*)d_in[1];
    const float* lstm_c      = (const float*)d_in[2];
    const float* lstm_h      = (const float*)d_in[3];
    const int*   coming_from = (const int*)d_in[5];
    const float* W_pre  = (const float*)d_in[7];
    const float* b_pre  = (const float*)d_in[8];
    const float* W_ih   = (const float*)d_in[9];
    const float* W_hh   = (const float*)d_in[10];
    const float* b_lstm = (const float*)d_in[11];
    const float* W_post = (const float*)d_in[12];
    const float* b_post = (const float*)d_in[13];
    unsigned short* wsp = (unsigned short*)d_ws;

    prep_weights<<<(WTOTAL + 255) / 256, 256, 0, stream>>>(W_pre, W_ih, W_hh, W_post, wsp);
    knet_fused<<<NCELL / 64, 256, 0, stream>>>(dyn_in, lat_prev, lstm_c, lstm_h, coming_from,
                                               wsp, b_pre, b_lstm, b_post, (float*)d_out);
}